// Round 2
// baseline (372.016 us; speedup 1.0000x reference)
//
#include <hip/hip_runtime.h>

typedef float v2f __attribute__((ext_vector_type(2)));

#define MAXN 256
#define NPTS 1024
#define MGRID 1024
#define NCH 16

__global__ __launch_bounds__(64)
void setconv_kernel(const float* __restrict__ xz,
                    const float* __restrict__ z,
                    const float* __restrict__ x_grid,
                    const float* __restrict__ log_scale,
                    float* __restrict__ out)
{
    const int i   = blockIdx.x;   // output row (grid column index)
    const int b   = blockIdx.y;   // batch
    const int tid = threadIdx.x;  // 0..63, one wave per block

    __shared__ float xz_l[MAXN];
    __shared__ float wi_l[MAXN];
    __shared__ int   n_l[MAXN];

    const float s2   = __expf(2.0f * log_scale[0]);   // s^2
    const float cexp = -0.5f / s2;
    const float r2   = 64.0f * s2;                    // cutoff: |exponent| < 32
    const float gi   = x_grid[i];
    const float h    = x_grid[1] - x_grid[0];

    // ---- gather contributing points via ballot compaction (single wave) ----
    int base = 0;
    for (int n0 = 0; n0 < NPTS; n0 += 64) {
        const int   n  = n0 + tid;
        const float xv = xz[b * NPTS + n];
        const float d  = xv - gi;
        const float d2 = d * d;
        const bool pred = d2 < r2;
        const unsigned long long m = __ballot(pred);
        if (pred) {
            const int idx = base + (int)__popcll(m & ((1ull << tid) - 1ull));
            if (idx < MAXN) {
                xz_l[idx] = xv;
                wi_l[idx] = __expf(cexp * d2);
                n_l[idx]  = n;
            }
        }
        base += (int)__popcll(m);
    }
    const int count = min(base, MAXN);
    __syncthreads();

    // ---- 256-wide, 4-aligned j-window around i (band half-width ~122) ----
    int jb = (i & ~3) - 128;
    jb = jb < 0 ? 0 : (jb > MGRID - 256 ? MGRID - 256 : jb);
    const float gj0 = x_grid[jb + 4 * tid];   // this thread's first j coord

    // w(x, gj0 + jj*h) = wi * E * K[jj] * T^jj
    const float tc  = -2.0f * cexp * h;       // T = exp(tc * d0)... note sign below
    const float ch2 = cexp * h * h;
    const float K1  = __expf(ch2);
    const float K2  = __expf(4.0f * ch2);
    const float K3  = __expf(9.0f * ch2);

    v2f   num2[4][8];
    float den[4] = {0.f, 0.f, 0.f, 0.f};
    #pragma unroll
    for (int jj = 0; jj < 4; ++jj)
        #pragma unroll
        for (int k = 0; k < 8; ++k) num2[jj][k] = (v2f){0.f, 0.f};

    const float* zb = z + (size_t)b * NPTS * NCH;

    // software-pipelined z-row prefetch (row is wave-uniform -> broadcast load)
    float4 c0, c1, c2, c3;
    if (count > 0) {
        const int n = __builtin_amdgcn_readfirstlane(n_l[0]);
        const float4* zr = (const float4*)(zb + (size_t)n * NCH);
        c0 = zr[0]; c1 = zr[1]; c2 = zr[2]; c3 = zr[3];
    }

    for (int t = 0; t < count; ++t) {
        const float4 a0 = c0, a1 = c1, a2 = c2, a3 = c3;
        if (t + 1 < count) {
            const int n = __builtin_amdgcn_readfirstlane(n_l[t + 1]);
            const float4* zr = (const float4*)(zb + (size_t)n * NCH);
            c0 = zr[0]; c1 = zr[1]; c2 = zr[2]; c3 = zr[3];
        }
        const float xzn = xz_l[t];
        const float wi  = wi_l[t];
        const float d0  = xzn - gj0;               // x - g_j(jj=0)
        const float E   = wi * __expf(cexp * d0 * d0);
        const float T   = __expf(tc * d0);         // exp(-2*c*h*d0)
        const float T2  = T * T;

        float p[4];
        p[0] = E;
        p[1] = E * K1 * T;
        p[2] = E * K2 * T2;
        p[3] = E * K3 * (T2 * T);

        const v2f za[8] = {{a0.x, a0.y}, {a0.z, a0.w}, {a1.x, a1.y}, {a1.z, a1.w},
                           {a2.x, a2.y}, {a2.z, a2.w}, {a3.x, a3.y}, {a3.z, a3.w}};
        #pragma unroll
        for (int jj = 0; jj < 4; ++jj) {
            den[jj] += p[jj];
            const v2f pp = {p[jj], p[jj]};
            #pragma unroll
            for (int k = 0; k < 8; ++k)
                num2[jj][k] = pp * za[k] + num2[jj][k];   // -> v_pk_fma_f32
        }
    }

    // ---------------- write phase ----------------
    // d_out layout: [x_grid (1024 floats)] [out (4,18,1024,1024)]
    float* big = out + MGRID;
    const size_t plane  = (size_t)MGRID * MGRID;
    const size_t rowoff = (size_t)i * MGRID;
    float* bbase = big + (size_t)b * 18 * plane;

    float rcp[4];
    #pragma unroll
    for (int jj = 0; jj < 4; ++jj) rcp[jj] = 1.0f / (den[jj] + 1e-8f);

    const int fw = (jb >> 2) + tid;   // this thread's float4 index in the row

    // channel 1: density
    ((float4*)(bbase + plane + rowoff))[fw] = make_float4(den[0], den[1], den[2], den[3]);
    // channels 2..17: ratios  (num2[jj][k2] holds channels 2k2, 2k2+1)
    #pragma unroll
    for (int k = 0; k < NCH; ++k) {
        const int k2 = k >> 1, lo = k & 1;
        ((float4*)(bbase + (size_t)(2 + k) * plane + rowoff))[fw] =
            make_float4(num2[0][k2][lo] * rcp[0], num2[1][k2][lo] * rcp[1],
                        num2[2][k2][lo] * rcp[2], num2[3][k2][lo] * rcp[3]);
    }

    // zeros outside the window, channels 1..17 (192 float4s per row each)
    const int wstart = jb >> 2;
    const float4 zero4 = make_float4(0.f, 0.f, 0.f, 0.f);
    for (int ch = 1; ch < 18; ++ch) {
        float4* rp = (float4*)(bbase + (size_t)ch * plane + rowoff);
        #pragma unroll
        for (int it = 0; it < 3; ++it) {
            const int idx = it * 64 + tid;                   // 0..191
            const int f   = (idx < wstart) ? idx : idx + 64; // skip the window's 64
            rp[f] = zero4;
        }
    }

    // channel 0: identity row (full row)
    {
        float4* rp = (float4*)(bbase + rowoff);
        #pragma unroll
        for (int it = 0; it < 4; ++it) {
            const int q  = it * 64 + tid;
            const int j0 = q * 4;
            float4 v;
            v.x = (j0 + 0 == i) ? 1.f : 0.f;
            v.y = (j0 + 1 == i) ? 1.f : 0.f;
            v.z = (j0 + 2 == i) ? 1.f : 0.f;
            v.w = (j0 + 3 == i) ? 1.f : 0.f;
            rp[q] = v;
        }
    }

    // output 0: x_grid passthrough (1024 floats)
    if (b == 0 && i < 16) {
        out[i * 64 + tid] = x_grid[i * 64 + tid];
    }
}

extern "C" void kernel_launch(void* const* d_in, const int* in_sizes, int n_in,
                              void* d_out, int out_size, void* d_ws, size_t ws_size,
                              hipStream_t stream)
{
    const float* xz = (const float*)d_in[0];
    const float* z  = (const float*)d_in[1];
    const float* xg = (const float*)d_in[2];
    const float* ls = (const float*)d_in[3];
    float* out = (float*)d_out;

    dim3 grid(MGRID, 4);
    setconv_kernel<<<grid, dim3(64), 0, stream>>>(xz, z, xg, ls, out);
}